// Round 4
// baseline (337.281 us; speedup 1.0000x reference)
//
#include <hip/hip_runtime.h>
#include <cstdint>
#include <math.h>

#pragma clang fp contract(off)

// Canny_1116691497316: per-channel Canny edges, out = x[:,indices] * tf
// x: (1,64,512,512) f32, indices: (32,) int32, out: (1,32,512,512) f32
//
// Decision variables (blur, sobel, mag, angle, thresholds) computed in f64 to
// match the numpy float64 oracle; classification flips are the only error mode
// that matters (each flip costs 0.5*|x| >> threshold).
//
// Buffer plan: d_out (32 MB) is reused as an f64 blur buffer for 16 channels
// at a time (16*262144*8 = 32 MB exactly); d_ws holds the weak/strong bitmaps
// (2 MB). Two blur+nms passes, then one hysteresis+multiply pass.

constexpr int HH = 512;
constexpr int WW = 512;
constexpr int HW = HH * WW;          // 262144 px per channel
constexpr int KCH = 32;              // selected channels
constexpr int HALF = 16;             // channels per pass
constexpr int WORDS = HW / 32;       // 8192 uint32 words per bitmap per channel

__device__ __forceinline__ int reflect_idx(int v) {
    // jnp.pad mode='reflect', pad 2, N=512: -1->1, -2->2, 512->510, 513->509
    return v < 0 ? -v : (v > 511 ? 1022 - v : v);
}
__device__ __forceinline__ int clampi(int v) {
    return v < 0 ? 0 : (v > 511 ? 511 : v);
}

// ---------------- Kernel 1: 5x5 gaussian blur (sigma=1, reflect pad), f64 ----------------
__global__ void blur_kernel(const float* __restrict__ x,
                            const int* __restrict__ idx,
                            double* __restrict__ blur, int k0) {
    #pragma clang fp contract(off)
    int p = blockIdx.x * blockDim.x + threadIdx.x;
    if (p >= HALF * HW) return;
    int k = p >> 18;            // p / HW
    int r = p & (HW - 1);
    int y = r >> 9, xx = r & 511;

    // g = exp(-0.5*t^2)/sum, t = -2..2, all in f64 (matches np)
    double g[5];
    {
        double s = 0.0;
        #pragma unroll
        for (int i = 0; i < 5; i++) {
            double t = (double)i - 2.0;
            g[i] = exp(-0.5 * t * t);
            s += g[i];
        }
        #pragma unroll
        for (int i = 0; i < 5; i++) g[i] = g[i] / s;
    }

    int ch = idx[k0 + k];
    const float* img = x + (size_t)ch * HW;

    double acc = 0.0;
    #pragma unroll
    for (int i = 0; i < 5; i++) {
        int cx = reflect_idx(xx + i - 2);
        double col = 0.0;
        #pragma unroll
        for (int j = 0; j < 5; j++) {
            int cy = reflect_idx(y + j - 2);
            col += g[j] * (double)img[cy * WW + cx];
        }
        acc += g[i] * col;
    }
    blur[p] = acc;
}

// ---------------- Kernel 2: sobel + mag + angle + NMS + thresholds, f64 ----------------
__device__ __forceinline__ void sobel_at(const double* __restrict__ b, int y, int x,
                                         double& gx, double& gy) {
    int ym = clampi(y - 1) * WW, y0 = y * WW, yp = clampi(y + 1) * WW;
    int xm = clampi(x - 1), xp = clampi(x + 1);
    double v00 = b[ym + xm], v01 = b[ym + x], v02 = b[ym + xp];
    double v10 = b[y0 + xm],                  v12 = b[y0 + xp];
    double v20 = b[yp + xm], v21 = b[yp + x], v22 = b[yp + xp];
    gx = ((((-v00 + v02) + (-2.0 * v10)) + (2.0 * v12)) + (-v20)) + v22;
    gy = ((((-v00 + (-2.0 * v01)) + (-v02)) + v20) + (2.0 * v21)) + v22;
}
__device__ __forceinline__ double mag_at(const double* __restrict__ b, int y, int x) {
    double gx, gy;
    sobel_at(b, y, x, gx, gy);
    return sqrt((gx * gx + gy * gy) + 1e-6);
}

// direction d -> neighbor offset (dy,dx), from _POS[i]-(1,1):
// d0:(0,1) d1:(1,1) d2:(1,0) d3:(1,-1) d4:(0,-1) d5:(-1,-1) d6:(-1,0) d7:(-1,1)
__device__ const int DYt[8] = {0, 1, 1, 1, 0, -1, -1, -1};
__device__ const int DXt[8] = {1, 1, 0, -1, -1, -1, 0, 1};

__global__ void nms_kernel(const double* __restrict__ blur,
                           unsigned long long* __restrict__ weakb,
                           unsigned long long* __restrict__ strongb, int k0) {
    #pragma clang fp contract(off)
    int p = blockIdx.x * blockDim.x + threadIdx.x;
    if (p >= HALF * HW) return;
    int k = p >> 18;
    int r = p & (HW - 1);
    int y = r >> 9, xx = r & 511;
    const double* b = blur + (size_t)k * HW;

    double gx, gy;
    sobel_at(b, y, xx, gx, gy);
    double m = sqrt((gx * gx + gy * gy) + 1e-6);

    // ang = round(atan2(gy,gx) * (180/pi) / 45); round-half-even = rint
    double t = atan2(gy, gx) * (180.0 / M_PI);
    t = t / 45.0;
    int ai = (int)rint(t);               // in {-4..4}
    int pos = ai & 7;                    // mod(ang, 8)
    int neg = (ai + 4) & 7;              // mod(ang+4, 8)

    int y1 = y + DYt[pos], x1 = xx + DXt[pos];
    int y2 = y + DYt[neg], x2 = xx + DXt[neg];
    // NMS conv is zero-padded: out-of-bounds neighbor contributes 0
    double mn1 = (y1 >= 0 && y1 < HH && x1 >= 0 && x1 < WW) ? mag_at(b, y1, x1) : 0.0;
    double mn2 = (y2 >= 0 && y2 < HH && x2 >= 0 && x2 < WW) ? mag_at(b, y2, x2) : 0.0;
    double sp = m - mn1, sn = m - mn2;
    bool keep = fmin(sp, sn) > 0.0;
    double mk = keep ? m : 0.0;

    bool strong = mk > 0.2;
    bool weak = (mk > 0.1) && !strong;

    unsigned long long wb = __ballot(weak);
    unsigned long long sb = __ballot(strong);
    if ((threadIdx.x & 63) == 0) {
        size_t gw = ((size_t)(k0 + k) * HW + r) >> 6;
        weakb[gw] = wb;
        strongb[gw] = sb;
    }
}

// ---------------- Kernel 3: hysteresis to fixed point + final multiply ----------------
// One block per channel. Strong bitmap in LDS (8192 words = 32KB); bit b of word
// w = pixel p = w*32+b; 16 words per 512-px row. Monotone 3x3 bitwise dilation
// until no change == reference while_loop fixed point (order-independent).
__global__ __launch_bounds__(1024) void hyst_kernel(const float* __restrict__ x,
                                                    const int* __restrict__ idx,
                                                    const unsigned int* __restrict__ weakb,
                                                    const unsigned int* __restrict__ strongb,
                                                    float* __restrict__ out) {
    int k = blockIdx.x;
    __shared__ unsigned int Sm[WORDS];
    __shared__ int s_changed;
    int tid = threadIdx.x;

    const unsigned int* wsrc = weakb + (size_t)k * WORDS;
    const unsigned int* ssrc = strongb + (size_t)k * WORDS;

    if (tid == 0) s_changed = 0;
    for (int i = tid; i < WORDS; i += 1024) Sm[i] = ssrc[i];
    unsigned int wreg[8];
    #pragma unroll
    for (int q = 0; q < 8; q++) wreg[q] = wsrc[tid * 8 + q];
    __syncthreads();

    for (;;) {
        int loc = 0;
        #pragma unroll
        for (int q = 0; q < 8; q++) {
            int w = tid * 8 + q;
            unsigned int s = Sm[w];
            unsigned int wk = wreg[q] & ~s;
            if (!wk) continue;
            int j = w & 15;
            unsigned int L = j ? Sm[w - 1] : 0u;
            unsigned int R = (j < 15) ? Sm[w + 1] : 0u;
            unsigned int D = (s << 1) | (L >> 31) | (s >> 1) | (R << 31);
            if (w >= 16) {
                unsigned int cu = Sm[w - 16];
                unsigned int Lu = j ? Sm[w - 17] : 0u;
                unsigned int Ru = (j < 15) ? Sm[w - 15] : 0u;
                D |= cu | (cu << 1) | (Lu >> 31) | (cu >> 1) | (Ru << 31);
            }
            if (w < WORDS - 16) {
                unsigned int cd = Sm[w + 16];
                unsigned int Ld = j ? Sm[w + 15] : 0u;
                unsigned int Rd = (j < 15) ? Sm[w + 17] : 0u;
                D |= cd | (cd << 1) | (Ld >> 31) | (cd >> 1) | (Rd << 31);
            }
            unsigned int promoted = wk & D;
            if (promoted) { Sm[w] = s | promoted; loc = 1; }
        }
        if (loc) s_changed = 1;
        __syncthreads();
        int chg = s_changed;
        __syncthreads();
        if (!chg) break;
        if (tid == 0) s_changed = 0;
        __syncthreads();
    }

    // out[k] = x[idx[k]] * tf ; tf: strong->1, weak(unpromoted)->0.5, else 0
    int ch = idx[k];
    const float* xs = x + (size_t)ch * HW;
    float* op = out + (size_t)k * HW;
    for (int p = tid; p < HW; p += 1024) {
        unsigned int s = Sm[p >> 5];
        unsigned int wm = wsrc[p >> 5];
        int bpos = p & 31;
        float tf = ((s >> bpos) & 1u) ? 1.0f : (((wm >> bpos) & 1u) ? 0.5f : 0.0f);
        op[p] = xs[p] * tf;
    }
}

extern "C" void kernel_launch(void* const* d_in, const int* in_sizes, int n_in,
                              void* d_out, int out_size, void* d_ws, size_t ws_size,
                              hipStream_t stream) {
    const float* x = (const float*)d_in[0];
    // d_in[1] = params (always 1 here; params==0 changes output shape, impossible
    // given out_size)
    const int* idx = (const int*)d_in[2];
    float* out = (float*)d_out;

    // d_out (32 MB) = f64 blur scratch for 16 channels per pass.
    double* blur = (double*)d_out;
    char* ws = (char*)d_ws;
    unsigned long long* weakb = (unsigned long long*)ws;                 // 1 MB
    unsigned long long* strongb = (unsigned long long*)(ws + 1048576);   // 1 MB

    int half_total = HALF * HW;  // 4,194,304
    for (int k0 = 0; k0 < KCH; k0 += HALF) {
        blur_kernel<<<half_total / 256, 256, 0, stream>>>(x, idx, blur, k0);
        nms_kernel<<<half_total / 256, 256, 0, stream>>>(blur, weakb, strongb, k0);
    }
    hyst_kernel<<<KCH, 1024, 0, stream>>>(x, idx, (const unsigned int*)weakb,
                                          (const unsigned int*)strongb, out);
}

// Round 5
// 174.785 us; speedup vs baseline: 1.9297x; 1.9297x over previous
//
#include <hip/hip_runtime.h>
#include <cstdint>
#include <math.h>

#pragma clang fp contract(off)

// Canny_1116691497316: per-channel Canny edges, out = x[:,indices] * tf
// x: (1,64,512,512) f32, indices: (32,) int32, out: (1,32,512,512) f32
//
// All decision variables in f64 (matches numpy f64 oracle; round-4 absmax 0.0).
// d_out (32 MB) = f64 blur scratch for 16 channels/pass; d_ws = 2 MB bitmaps.
// Pipeline: 2x(blur -> nms) -> hyst_iterate (bitmap closure, 32 blocks)
//           -> mul (full grid).

constexpr int HH = 512;
constexpr int WW = 512;
constexpr int HW = HH * WW;          // 262144 px per channel
constexpr int KCH = 32;              // selected channels
constexpr int HALF = 16;             // channels per pass
constexpr int WORDS = HW / 32;       // 8192 uint32 words per bitmap per channel

// f64 gaussian weights, exact value chain of the reference:
// g_i = exp(-0.5*t^2), s = ((((g0+g1)+g2)+g3)+g4, w_i = g_i/s  (all IEEE f64)
constexpr double E2 = 0.13533528323661269189;  // exp(-2.0), correctly rounded
constexpr double E1 = 0.60653065971263342360;  // exp(-0.5), correctly rounded
constexpr double GS = ((((E2 + E1) + 1.0) + E1) + E2);
constexpr double GW0 = E2 / GS, GW1 = E1 / GS, GW2 = 1.0 / GS;

// tan(22.5deg) = sqrt(2)-1, tan(67.5deg) = sqrt(2)+1
constexpr double T1 = 0.4142135623730950488;
constexpr double T2 = 2.4142135623730950488;

__device__ __forceinline__ int reflect_idx(int v) {
    // jnp.pad mode='reflect', pad 2, N=512: -1->1, -2->2, 512->510, 513->509
    return v < 0 ? -v : (v > 511 ? 1022 - v : v);
}
__device__ __forceinline__ int clampi(int v) {
    return v < 0 ? 0 : (v > 511 ? 511 : v);
}

// ---------------- Kernel 1: 5x5 gaussian blur (sigma=1, reflect pad), f64 ----------------
__global__ void blur_kernel(const float* __restrict__ x,
                            const int* __restrict__ idx,
                            double* __restrict__ blur, int k0) {
    #pragma clang fp contract(off)
    int p = blockIdx.x * blockDim.x + threadIdx.x;
    if (p >= HALF * HW) return;
    int k = p >> 18;            // p / HW
    int r = p & (HW - 1);
    int y = r >> 9, xx = r & 511;

    const double g[5] = {GW0, GW1, GW2, GW1, GW0};

    int ch = idx[k0 + k];
    const float* img = x + (size_t)ch * HW;

    double acc = 0.0;
    #pragma unroll
    for (int i = 0; i < 5; i++) {
        int cx = reflect_idx(xx + i - 2);
        double col = 0.0;
        #pragma unroll
        for (int j = 0; j < 5; j++) {
            int cy = reflect_idx(y + j - 2);
            col += g[j] * (double)img[cy * WW + cx];
        }
        acc += g[i] * col;
    }
    blur[p] = acc;
}

// ---------------- Kernel 2: sobel + mag + axis + NMS + thresholds, f64 ----------------
__device__ __forceinline__ void sobel_at(const double* __restrict__ b, int y, int x,
                                         double& gx, double& gy) {
    int ym = clampi(y - 1) * WW, y0 = y * WW, yp = clampi(y + 1) * WW;
    int xm = clampi(x - 1), xp = clampi(x + 1);
    double v00 = b[ym + xm], v01 = b[ym + x], v02 = b[ym + xp];
    double v10 = b[y0 + xm],                  v12 = b[y0 + xp];
    double v20 = b[yp + xm], v21 = b[yp + x], v22 = b[yp + xp];
    gx = ((((-v00 + v02) + (-2.0 * v10)) + (2.0 * v12)) + (-v20)) + v22;
    gy = ((((-v00 + (-2.0 * v01)) + (-v02)) + v20) + (2.0 * v21)) + v22;
}
__device__ __forceinline__ double mag_at(const double* __restrict__ b, int y, int x) {
    double gx, gy;
    sobel_at(b, y, x, gx, gy);
    return sqrt((gx * gx + gy * gy) + 1e-6);
}

// axis a in {0..3}: neighbor pair for NMS. Equivalent to
// rint(atan2(gy,gx)*(180/pi)/45) mod 4 (pos/neg are always the opposite pair).
// a0:(0,+-1) a1:(+-1,+-1 same sign) a2:(+-1,0) a3:(+-1,-+1)
__device__ const int AY1[4] = {0, 1, 1, 1};
__device__ const int AX1[4] = {1, 1, 0, -1};

__global__ void nms_kernel(const double* __restrict__ blur,
                           unsigned long long* __restrict__ weakb,
                           unsigned long long* __restrict__ strongb, int k0) {
    #pragma clang fp contract(off)
    int p = blockIdx.x * blockDim.x + threadIdx.x;
    if (p >= HALF * HW) return;
    int k = p >> 18;
    int r = p & (HW - 1);
    int y = r >> 9, xx = r & 511;
    const double* b = blur + (size_t)k * HW;

    double gx, gy;
    sobel_at(b, y, xx, gx, gy);
    double m = sqrt((gx * gx + gy * gy) + 1e-6);

    // sector: fold gy<0 (angle+-180 keeps axis); then compare |gy| vs tan
    // boundaries. Matches the reference's rint(angle/45)&3 away from ~1-ulp
    // boundary bands (flip prob ~1e-14/px).
    double ax = fabs(gx), ay = fabs(gy);
    int axis;
    if (ay < T1 * ax) axis = 0;
    else if (ay > T2 * ax) axis = 2;
    else {
        double gxf = (gy < 0.0) ? -gx : gx;
        axis = (gxf > 0.0) ? 1 : 3;
    }

    int dy = AY1[axis], dx = AX1[axis];
    int y1 = y + dy, x1 = xx + dx;
    int y2 = y - dy, x2 = xx - dx;
    // NMS conv is zero-padded: out-of-bounds neighbor contributes 0
    double mn1 = (y1 >= 0 && y1 < HH && x1 >= 0 && x1 < WW) ? mag_at(b, y1, x1) : 0.0;
    double mn2 = (y2 >= 0 && y2 < HH && x2 >= 0 && x2 < WW) ? mag_at(b, y2, x2) : 0.0;
    double sp = m - mn1, sn = m - mn2;
    bool keep = fmin(sp, sn) > 0.0;
    double mk = keep ? m : 0.0;

    bool strong = mk > 0.2;
    bool weak = (mk > 0.1) && !strong;

    unsigned long long wb = __ballot(weak);
    unsigned long long sb = __ballot(strong);
    if ((threadIdx.x & 63) == 0) {
        size_t gw = ((size_t)(k0 + k) * HW + r) >> 6;
        weakb[gw] = wb;
        strongb[gw] = sb;
    }
}

// ---------------- Kernel 3: hysteresis closure on bitmaps ----------------
// One block per channel; strong bitmap in LDS; monotone 3x3 bitwise dilation
// through the weak mask until fixed point; write closure back to strongb.
__global__ __launch_bounds__(1024) void hyst_iterate(const unsigned int* __restrict__ weakb,
                                                     unsigned int* __restrict__ strongb) {
    int k = blockIdx.x;
    __shared__ unsigned int Sm[WORDS];
    __shared__ int s_changed;
    int tid = threadIdx.x;

    const unsigned int* wsrc = weakb + (size_t)k * WORDS;
    unsigned int* ssrc = strongb + (size_t)k * WORDS;

    if (tid == 0) s_changed = 0;
    for (int i = tid; i < WORDS; i += 1024) Sm[i] = ssrc[i];
    unsigned int wreg[8];
    #pragma unroll
    for (int q = 0; q < 8; q++) wreg[q] = wsrc[tid * 8 + q];
    __syncthreads();

    for (;;) {
        int loc = 0;
        #pragma unroll
        for (int q = 0; q < 8; q++) {
            int w = tid * 8 + q;
            unsigned int s = Sm[w];
            unsigned int wk = wreg[q] & ~s;
            if (!wk) continue;
            int j = w & 15;  // word column within 16-word row
            unsigned int L = j ? Sm[w - 1] : 0u;
            unsigned int R = (j < 15) ? Sm[w + 1] : 0u;
            unsigned int D = (s << 1) | (L >> 31) | (s >> 1) | (R << 31);
            if (w >= 16) {
                unsigned int cu = Sm[w - 16];
                unsigned int Lu = j ? Sm[w - 17] : 0u;
                unsigned int Ru = (j < 15) ? Sm[w - 15] : 0u;
                D |= cu | (cu << 1) | (Lu >> 31) | (cu >> 1) | (Ru << 31);
            }
            if (w < WORDS - 16) {
                unsigned int cd = Sm[w + 16];
                unsigned int Ld = j ? Sm[w + 15] : 0u;
                unsigned int Rd = (j < 15) ? Sm[w + 17] : 0u;
                D |= cd | (cd << 1) | (Ld >> 31) | (cd >> 1) | (Rd << 31);
            }
            unsigned int promoted = wk & D;
            if (promoted) { Sm[w] = s | promoted; loc = 1; }
        }
        if (loc) s_changed = 1;
        __syncthreads();
        int chg = s_changed;
        __syncthreads();
        if (!chg) break;
        if (tid == 0) s_changed = 0;
        __syncthreads();
    }

    for (int i = tid; i < WORDS; i += 1024) ssrc[i] = Sm[i];
}

// ---------------- Kernel 4: out = x[:,indices] * tf, full grid, float4 ----------------
__global__ void mul_kernel(const float* __restrict__ x,
                           const int* __restrict__ idx,
                           const unsigned int* __restrict__ weakb,
                           const unsigned int* __restrict__ strongb,
                           float* __restrict__ out) {
    int gid = blockIdx.x * blockDim.x + threadIdx.x;
    int p = gid * 4;
    if (p >= KCH * HW) return;
    int k = p >> 18;
    int r = p & (HW - 1);
    int ch = idx[k];

    unsigned int sw = strongb[p >> 5];
    unsigned int ww = weakb[p >> 5];
    int b0 = p & 31;

    const float4 xv = *reinterpret_cast<const float4*>(x + (size_t)ch * HW + r);
    float t[4];
    #pragma unroll
    for (int i = 0; i < 4; i++) {
        int b = b0 + i;
        t[i] = ((sw >> b) & 1u) ? 1.0f : (((ww >> b) & 1u) ? 0.5f : 0.0f);
    }
    float4 o;
    o.x = xv.x * t[0];
    o.y = xv.y * t[1];
    o.z = xv.z * t[2];
    o.w = xv.w * t[3];
    *reinterpret_cast<float4*>(out + (size_t)p) = o;
}

extern "C" void kernel_launch(void* const* d_in, const int* in_sizes, int n_in,
                              void* d_out, int out_size, void* d_ws, size_t ws_size,
                              hipStream_t stream) {
    const float* x = (const float*)d_in[0];
    // d_in[1] = params (always 1 here; params==0 changes output shape, impossible
    // given out_size)
    const int* idx = (const int*)d_in[2];
    float* out = (float*)d_out;

    double* blur = (double*)d_out;   // 32 MB f64 scratch, 16 channels/pass
    char* ws = (char*)d_ws;
    unsigned long long* weakb = (unsigned long long*)ws;                 // 1 MB
    unsigned long long* strongb = (unsigned long long*)(ws + 1048576);   // 1 MB

    int half_total = HALF * HW;  // 4,194,304
    for (int k0 = 0; k0 < KCH; k0 += HALF) {
        blur_kernel<<<half_total / 256, 256, 0, stream>>>(x, idx, blur, k0);
        nms_kernel<<<half_total / 256, 256, 0, stream>>>(blur, weakb, strongb, k0);
    }
    hyst_iterate<<<KCH, 1024, 0, stream>>>((const unsigned int*)weakb,
                                           (unsigned int*)strongb);
    mul_kernel<<<(KCH * HW / 4) / 256, 256, 0, stream>>>(x, idx,
                                                         (const unsigned int*)weakb,
                                                         (const unsigned int*)strongb,
                                                         out);
}

// Round 6
// 106.319 us; speedup vs baseline: 3.1724x; 1.6440x over previous
//
#include <hip/hip_runtime.h>
#include <cstdint>
#include <math.h>

#pragma clang fp contract(off)

// Canny_1116691497316: per-channel Canny edges, out = x[:,indices] * tf
// x: (1,64,512,512) f32, indices: (32,) int32, out: (1,32,512,512) f32
//
// All decision variables in f64 (matches numpy f64 oracle; rounds 4-5 absmax 0.0).
// Round 6: blur+sobel+mag+NMS fused into one LDS-tiled kernel (no f64 global
// blur buffer). Pipeline: canny_fused -> hyst_iterate -> mul. d_ws = 2 MB bitmaps.

constexpr int HH = 512;
constexpr int WW = 512;
constexpr int HW = HH * WW;          // 262144 px per channel
constexpr int KCH = 32;              // selected channels
constexpr int WORDS = HW / 32;       // 8192 uint32 words per bitmap per channel

constexpr int TY = 32;               // output tile rows
constexpr int TX = 64;               // output tile cols
constexpr int NTY = HH / TY;         // 16
constexpr int NTX = WW / TX;         // 8

// f64 gaussian weights, exact value chain of the reference:
// g_i = exp(-0.5*t^2), s = ((((g0+g1)+g2)+g3)+g4), w_i = g_i/s (IEEE f64)
constexpr double E2 = 0.13533528323661269189;  // exp(-2.0), correctly rounded
constexpr double E1 = 0.60653065971263342360;  // exp(-0.5), correctly rounded
constexpr double GS = ((((E2 + E1) + 1.0) + E1) + E2);
constexpr double GW0 = E2 / GS, GW1 = E1 / GS, GW2 = 1.0 / GS;

// tan(22.5deg) = sqrt(2)-1, tan(67.5deg) = sqrt(2)+1
constexpr double T1 = 0.4142135623730950488;
constexpr double T2 = 2.4142135623730950488;

__device__ __forceinline__ int reflect_idx(int v) {
    // jnp.pad mode='reflect', N=512 (valid for |v| overhang <= 4 here)
    return v < 0 ? -v : (v > 511 ? 1022 - v : v);
}
__device__ __forceinline__ int clampi(int v) {
    return v < 0 ? 0 : (v > 511 ? 511 : v);
}

// axis a in {0..3}: NMS neighbor pair, == rint(atan2(gy,gx)*(180/pi)/45) mod 4
__device__ const int AY1[4] = {0, 1, 1, 1};
__device__ const int AX1[4] = {1, 1, 0, -1};

// ---------------- Kernel 1: fused blur + sobel + mag + NMS + thresholds ----------------
// One 256-thread block per 32x64 output tile. LDS: input 40x72 f32 (halo 4),
// blur 36x68 f64 (halo 2), mag 34x66 f64 (halo 1). 49,056 B total.
__global__ __launch_bounds__(256) void canny_fused(const float* __restrict__ x,
                                                   const int* __restrict__ idx,
                                                   unsigned long long* __restrict__ weakb,
                                                   unsigned long long* __restrict__ strongb) {
    #pragma clang fp contract(off)
    __shared__ float  in_s[TY + 8][TX + 8];   // [40][72]
    __shared__ double bl_s[TY + 4][TX + 4];   // [36][68]
    __shared__ double mg_s[TY + 2][TX + 2];   // [34][66]

    int tile = blockIdx.x;
    int k = tile >> 7;                 // 128 tiles per channel
    int t = tile & 127;
    int ty0 = (t >> 3) * TY;           // 16 row-tiles
    int tx0 = (t & 7) * TX;            // 8 col-tiles
    int tid = threadIdx.x;

    int ch = idx[k];
    const float* img = x + (size_t)ch * HW;

    // ---- load input tile (reflect-mapped == reference's pad-then-conv) ----
    for (int i = tid; i < (TY + 8) * (TX + 8); i += 256) {
        int a = i / (TX + 8), b = i - a * (TX + 8);
        int gy = reflect_idx(ty0 - 4 + a);
        int gx = reflect_idx(tx0 - 4 + b);
        in_s[a][b] = img[gy * WW + gx];
    }
    __syncthreads();

    // ---- blur tile: rows inner (j), cols outer (i) — reference conv order ----
    const double g[5] = {GW0, GW1, GW2, GW1, GW0};
    for (int c = tid; c < (TY + 4) * (TX + 4); c += 256) {
        int a = c / (TX + 4), b = c - a * (TX + 4);
        double acc = 0.0;
        #pragma unroll
        for (int i = 0; i < 5; i++) {
            double col = 0.0;
            #pragma unroll
            for (int j = 0; j < 5; j++) {
                col += g[j] * (double)in_s[a + j][b + i];
            }
            acc += g[i] * col;
        }
        bl_s[a][b] = acc;
    }
    __syncthreads();

    // ---- mag tile: sobel (replicate-clamped rows/cols) + sqrt, f64 ----
    for (int c = tid; c < (TY + 2) * (TX + 2); c += 256) {
        int am = c / (TX + 2), bm = c - am * (TX + 2);
        int u = ty0 - 1 + am, v = tx0 - 1 + bm;       // global coords
        int ru = clampi(u - 1) - (ty0 - 2);
        int r0 = u - (ty0 - 2);                        // center row unclamped (as ref)
        int rd = clampi(u + 1) - (ty0 - 2);
        int cl = clampi(v - 1) - (tx0 - 2);
        int c0 = v - (tx0 - 2);
        int cr = clampi(v + 1) - (tx0 - 2);
        double v00 = bl_s[ru][cl], v01 = bl_s[ru][c0], v02 = bl_s[ru][cr];
        double v10 = bl_s[r0][cl],                      v12 = bl_s[r0][cr];
        double v20 = bl_s[rd][cl], v21 = bl_s[rd][c0], v22 = bl_s[rd][cr];
        double gxv = ((((-v00 + v02) + (-2.0 * v10)) + (2.0 * v12)) + (-v20)) + v22;
        double gyv = ((((-v00 + (-2.0 * v01)) + (-v02)) + v20) + (2.0 * v21)) + v22;
        mg_s[am][bm] = sqrt((gxv * gxv + gyv * gyv) + 1e-6);
    }
    __syncthreads();

    // ---- NMS + double threshold + ballot ----
    for (int q8 = 0; q8 < TY * TX / 256; q8++) {
        int l = q8 * 256 + tid;
        int oy = l >> 6, ox = l & 63;                  // wave = one 64-px row span
        int gy = ty0 + oy, gx = tx0 + ox;

        // center sobel (for sector); center mag from LDS
        int ru = clampi(gy - 1) - (ty0 - 2);
        int r0 = gy - (ty0 - 2);
        int rd = clampi(gy + 1) - (ty0 - 2);
        int cl = clampi(gx - 1) - (tx0 - 2);
        int c0 = gx - (tx0 - 2);
        int cr = clampi(gx + 1) - (tx0 - 2);
        double v00 = bl_s[ru][cl], v01 = bl_s[ru][c0], v02 = bl_s[ru][cr];
        double v10 = bl_s[r0][cl],                      v12 = bl_s[r0][cr];
        double v20 = bl_s[rd][cl], v21 = bl_s[rd][c0], v22 = bl_s[rd][cr];
        double gxv = ((((-v00 + v02) + (-2.0 * v10)) + (2.0 * v12)) + (-v20)) + v22;
        double gyv = ((((-v00 + (-2.0 * v01)) + (-v02)) + v20) + (2.0 * v21)) + v22;
        double m = mg_s[oy + 1][ox + 1];

        // sector: fold gy<0; compare |gy| vs tan boundaries (round-5 logic, abs=0)
        double ax = fabs(gxv), ay = fabs(gyv);
        int axis;
        if (ay < T1 * ax) axis = 0;
        else if (ay > T2 * ax) axis = 2;
        else {
            double gxf = (gyv < 0.0) ? -gxv : gxv;
            axis = (gxf > 0.0) ? 1 : 3;
        }
        int dy = AY1[axis], dx = AX1[axis];

        int y1 = gy + dy, x1 = gx + dx;
        int y2 = gy - dy, x2 = gx - dx;
        // NMS conv zero-padded: out-of-image neighbor contributes 0
        double mn1 = (y1 >= 0 && y1 < HH && x1 >= 0 && x1 < WW)
                         ? mg_s[oy + 1 + dy][ox + 1 + dx] : 0.0;
        double mn2 = (y2 >= 0 && y2 < HH && x2 >= 0 && x2 < WW)
                         ? mg_s[oy + 1 - dy][ox + 1 - dx] : 0.0;
        bool keep = fmin(m - mn1, m - mn2) > 0.0;
        double mk = keep ? m : 0.0;

        bool strong = mk > 0.2;
        bool weak = (mk > 0.1) && !strong;

        unsigned long long wb = __ballot(weak);
        unsigned long long sb = __ballot(strong);
        if ((tid & 63) == 0) {
            size_t w64 = ((size_t)k * HW + (size_t)gy * WW + tx0) >> 6;
            weakb[w64] = wb;
            strongb[w64] = sb;
        }
    }
}

// ---------------- Kernel 2: hysteresis closure on bitmaps ----------------
// One block per channel; strong bitmap in LDS; monotone 3x3 bitwise dilation
// through the weak mask until fixed point (== reference while_loop fixed point).
__global__ __launch_bounds__(1024) void hyst_iterate(const unsigned int* __restrict__ weakb,
                                                     unsigned int* __restrict__ strongb) {
    int k = blockIdx.x;
    __shared__ unsigned int Sm[WORDS];
    __shared__ int s_changed;
    int tid = threadIdx.x;

    const unsigned int* wsrc = weakb + (size_t)k * WORDS;
    unsigned int* ssrc = strongb + (size_t)k * WORDS;

    if (tid == 0) s_changed = 0;
    for (int i = tid; i < WORDS; i += 1024) Sm[i] = ssrc[i];
    unsigned int wreg[8];
    #pragma unroll
    for (int q = 0; q < 8; q++) wreg[q] = wsrc[tid * 8 + q];
    __syncthreads();

    for (;;) {
        int loc = 0;
        #pragma unroll
        for (int q = 0; q < 8; q++) {
            int w = tid * 8 + q;
            unsigned int s = Sm[w];
            unsigned int wk = wreg[q] & ~s;
            if (!wk) continue;
            int j = w & 15;  // word column within 16-word row
            unsigned int L = j ? Sm[w - 1] : 0u;
            unsigned int R = (j < 15) ? Sm[w + 1] : 0u;
            unsigned int D = (s << 1) | (L >> 31) | (s >> 1) | (R << 31);
            if (w >= 16) {
                unsigned int cu = Sm[w - 16];
                unsigned int Lu = j ? Sm[w - 17] : 0u;
                unsigned int Ru = (j < 15) ? Sm[w - 15] : 0u;
                D |= cu | (cu << 1) | (Lu >> 31) | (cu >> 1) | (Ru << 31);
            }
            if (w < WORDS - 16) {
                unsigned int cd = Sm[w + 16];
                unsigned int Ld = j ? Sm[w + 15] : 0u;
                unsigned int Rd = (j < 15) ? Sm[w + 17] : 0u;
                D |= cd | (cd << 1) | (Ld >> 31) | (cd >> 1) | (Rd << 31);
            }
            unsigned int promoted = wk & D;
            if (promoted) { Sm[w] = s | promoted; loc = 1; }
        }
        if (loc) s_changed = 1;
        __syncthreads();
        int chg = s_changed;
        __syncthreads();
        if (!chg) break;
        if (tid == 0) s_changed = 0;
        __syncthreads();
    }

    for (int i = tid; i < WORDS; i += 1024) ssrc[i] = Sm[i];
}

// ---------------- Kernel 3: out = x[:,indices] * tf, full grid, float4 ----------------
__global__ void mul_kernel(const float* __restrict__ x,
                           const int* __restrict__ idx,
                           const unsigned int* __restrict__ weakb,
                           const unsigned int* __restrict__ strongb,
                           float* __restrict__ out) {
    int gid = blockIdx.x * blockDim.x + threadIdx.x;
    int p = gid * 4;
    if (p >= KCH * HW) return;
    int k = p >> 18;
    int r = p & (HW - 1);
    int ch = idx[k];

    unsigned int sw = strongb[p >> 5];
    unsigned int ww = weakb[p >> 5];
    int b0 = p & 31;

    const float4 xv = *reinterpret_cast<const float4*>(x + (size_t)ch * HW + r);
    float t[4];
    #pragma unroll
    for (int i = 0; i < 4; i++) {
        int b = b0 + i;
        t[i] = ((sw >> b) & 1u) ? 1.0f : (((ww >> b) & 1u) ? 0.5f : 0.0f);
    }
    float4 o;
    o.x = xv.x * t[0];
    o.y = xv.y * t[1];
    o.z = xv.z * t[2];
    o.w = xv.w * t[3];
    *reinterpret_cast<float4*>(out + (size_t)p) = o;
}

extern "C" void kernel_launch(void* const* d_in, const int* in_sizes, int n_in,
                              void* d_out, int out_size, void* d_ws, size_t ws_size,
                              hipStream_t stream) {
    const float* x = (const float*)d_in[0];
    // d_in[1] = params (always 1 here; params==0 changes output shape, impossible
    // given out_size)
    const int* idx = (const int*)d_in[2];
    float* out = (float*)d_out;

    char* ws = (char*)d_ws;
    unsigned long long* weakb = (unsigned long long*)ws;                 // 1 MB
    unsigned long long* strongb = (unsigned long long*)(ws + 1048576);   // 1 MB

    int ntiles = KCH * NTY * NTX;  // 32 * 128 = 4096
    canny_fused<<<ntiles, 256, 0, stream>>>(x, idx, weakb, strongb);
    hyst_iterate<<<KCH, 1024, 0, stream>>>((const unsigned int*)weakb,
                                           (unsigned int*)strongb);
    mul_kernel<<<(KCH * HW / 4) / 256, 256, 0, stream>>>(x, idx,
                                                         (const unsigned int*)weakb,
                                                         (const unsigned int*)strongb,
                                                         out);
}